// Round 1
// baseline (502.380 us; speedup 1.0000x reference)
//
#include <hip/hip_runtime.h>
#include <hip/hip_bf16.h>
#include <hip/hip_fp8.h>
#include <hip/hip_cooperative_groups.h>

namespace cg = cooperative_groups;

typedef __attribute__((ext_vector_type(4))) float f32x4;
typedef long long i64;

// exp(v/T - 5) with T=0.2  ==  exp2( (v-1) * 5*log2(e) )
#define EXP_SCALE 7.213475204444817f

__device__ __forceinline__ float fast_exp2(float x) {
#if __has_builtin(__builtin_amdgcn_exp2f)
  return __builtin_amdgcn_exp2f(x);
#else
  return exp2f(x);
#endif
}

// z is stored as fp8 e4m3, SWIZZLED in MFMA-fragment order (byte units):
//   byte addr = tile*2048 + kk*512 + slot*8 + rem
// tile = row>>4, c = row&15; element e: kk = e>>5, q = (e>>3)&3, rem = e&7,
// slot = q*16 + c. A wave (lane = q*16+c) loads one (tile,kk) fragment as
// one contiguous 512B load (8B/lane dwordx2).

// ---------------- phase 1: L2-normalize one 16-row tile -> swizzled fp8 z ----
__device__ __forceinline__ void do_normalize(
    int tile, const float* __restrict__ emb_i, const float* __restrict__ emb_j,
    unsigned char* __restrict__ z, float* __restrict__ rowsum,
    float* __restrict__ out)
{
  if (tile == 0 && threadIdx.x == 0) out[0] = 0.0f;
  if (threadIdx.x < 16) rowsum[(tile << 4) + threadIdx.x] = 0.0f;
  const int t = threadIdx.x;
  const int c = t >> 4;               // row within tile (0..15)
  const int sub = t & 15;             // 8-element block within row
  const int row = (tile << 4) + c;
  const float* src = (row < 4096) ? (emb_i + row * 128) : (emb_j + (row - 4096) * 128);
  float4 v0 = reinterpret_cast<const float4*>(src)[sub * 2];
  float4 v1 = reinterpret_cast<const float4*>(src)[sub * 2 + 1];
  float ss = v0.x*v0.x + v0.y*v0.y + v0.z*v0.z + v0.w*v0.w
           + v1.x*v1.x + v1.y*v1.y + v1.z*v1.z + v1.w*v1.w;
  #pragma unroll
  for (int m = 1; m < 16; m <<= 1) ss += __shfl_xor(ss, m, 64);
  float rinv = 1.0f / sqrtf(ss);
  unsigned char st[8];
  st[0] = __hip_fp8_e4m3(v0.x * rinv).__x;
  st[1] = __hip_fp8_e4m3(v0.y * rinv).__x;
  st[2] = __hip_fp8_e4m3(v0.z * rinv).__x;
  st[3] = __hip_fp8_e4m3(v0.w * rinv).__x;
  st[4] = __hip_fp8_e4m3(v1.x * rinv).__x;
  st[5] = __hip_fp8_e4m3(v1.y * rinv).__x;
  st[6] = __hip_fp8_e4m3(v1.z * rinv).__x;
  st[7] = __hip_fp8_e4m3(v1.w * rinv).__x;
  // swizzled dst: kk = sub>>2, q = sub&3, slot = q*16 + c
  unsigned char* dst = z + tile * 2048 + (sub >> 2) * 512 +
                       (((sub & 3) << 4) + c) * 8;
  *reinterpret_cast<i64*>(dst) = *reinterpret_cast<i64*>(st);
}

// ---------------- phase 2: one 64x512 cell of the sim/exp accumulation ------
// cell exists iff rb < 8(ch+1), ch 0..15 -> 1088 cells (53% of full work).
// A fragments straight from global (16 x 512B contiguous wave loads). Row-sums
// atomicAdd into rowsum; strictly-upper cells also atomicAdd column sums
// (transposed rows). Diagonal exp term (==1 for unit rows) kept; finish
// subtracts 1.
__device__ void do_cell(int bid, const unsigned char* __restrict__ z,
                        float* __restrict__ rowsum, float* __restrict__ rowpos)
{
  const int w = threadIdx.x >> 6;
  const int lane = threadIdx.x & 63;
  const int q = lane >> 4;
  const int c = lane & 15;

  // cell id -> (ch, rb): start(ch) = 4ch(ch+1), cells(ch) = 8(ch+1)
  int ch = 0;
  while (bid >= 4 * (ch + 1) * (ch + 2)) ++ch;
  const int rb = bid - 4 * ch * (ch + 1);          // 0 .. 8ch+7
  const int R0 = rb << 6;                          // 64-row block
  const bool upper = (rb < (ch << 3));             // strictly above diagonal band

  // ---- A fragments straight from global: 16 contiguous 512B loads ----
  i64 a[4][4];
  {
    const unsigned char* ap = z + (R0 >> 4) * 2048 + (lane << 3);
    #pragma unroll
    for (int rg = 0; rg < 4; ++rg)
      #pragma unroll
      for (int kk = 0; kk < 4; ++kk)
        a[rg][kk] = *reinterpret_cast<const i64*>(ap + rg * 2048 + kk * 512);
  }

  float acc[4][4];
  #pragma unroll
  for (int rg = 0; rg < 4; ++rg)
    #pragma unroll
    for (int e = 0; e < 4; ++e) acc[rg][e] = 0.0f;
  float pacc[4] = {0.f, 0.f, 0.f, 0.f};
  float colp[8];
  #pragma unroll
  for (int i = 0; i < 8; ++i) colp[i] = 0.0f;

  __shared__ float lsum[4][64];
  __shared__ float lpos[4][16];

  // wave w walks 16-col tiles ct = 32ch + w + 4i, i = 0..7
  const int ct0 = (ch << 5) + w;
  const unsigned char* bwave = z + ct0 * 2048 + (lane << 3);

  // positive tile: owned by this cell iff its 32-tile chunk matches.
  const int pos0t = ((R0 + 4096) & 8191) >> 4;
  const int ipb = ((pos0t >> 5) == ch) ? ((pos0t & 31) >> 2) : -99;

  i64 b0[4], b1[4];
  auto ldb = [&](i64 (&dst)[4], int idx) {
    const unsigned char* p = bwave + idx * 8192;   // stride 4 tiles = 8KB
    dst[0] = *reinterpret_cast<const i64*>(p);
    dst[1] = *reinterpret_cast<const i64*>(p + 512);
    dst[2] = *reinterpret_cast<const i64*>(p + 1024);
    dst[3] = *reinterpret_cast<const i64*>(p + 1536);
  };

  auto process = [&](const i64 (&bb)[4], int i) {
    f32x4 cc[4];
    #pragma unroll
    for (int rr = 0; rr < 4; ++rr) cc[rr] = f32x4{0.f, 0.f, 0.f, 0.f};
    #pragma unroll
    for (int kk = 0; kk < 4; ++kk)
      #pragma unroll
      for (int rr = 0; rr < 4; ++rr)
        cc[rr] = __builtin_amdgcn_mfma_f32_16x16x32_fp8_fp8(
            a[rr][kk], bb[kk], cc[rr], 0, 0, 0);
    float cp0 = 0.0f, cp1 = 0.0f;       // two chains to cut dep latency
    #pragma unroll
    for (int rr = 0; rr < 4; ++rr)
      #pragma unroll
      for (int e = 0; e < 4; ++e) {
        float tv = fast_exp2(__builtin_fmaf(cc[rr][e], EXP_SCALE, -EXP_SCALE));
        acc[rr][e] += tv;
        if (upper) { if (rr & 1) cp1 += tv; else cp0 += tv; }
      }
    if (upper) colp[i] = cp0 + cp1;     // shfl deferred out of the loop
    if (i == ipb) {                     // rare, wave-uniform
      #pragma unroll
      for (int rr = 0; rr < 4; ++rr) {
        if (rr == w) {
          #pragma unroll
          for (int e = 0; e < 4; ++e)
            if (c == ((q << 2) + e)) pacc[e] = cc[rr][e] * 5.0f;
        }
      }
    }
  };

  ldb(b0, 0);
  #pragma unroll 1
  for (int i = 0; i < 8; i += 2) {
    ldb(b1, i + 1);
    process(b0, i);
    if (i + 2 < 8) ldb(b0, i + 2);
    process(b1, i + 1);
  }

  // Deferred colsum reduction: 8 independent values, shfls pipeline
  if (upper) {
    #pragma unroll
    for (int i = 0; i < 8; ++i) {
      float v = colp[i];
      v += __shfl_xor(v, 16, 64);
      v += __shfl_xor(v, 32, 64);
      if (lane < 16)                    // col = (ct0+4i)*16 + c
        atomicAdd(&rowsum[((ct0 + (i << 2)) << 4) + c], v);
    }
  }

  // Reduce row-sums over the 16 cols per tile (c-group: xor 1,2,4,8)
  #pragma unroll
  for (int m = 1; m < 16; m <<= 1) {
    #pragma unroll
    for (int rg = 0; rg < 4; ++rg)
      #pragma unroll
      for (int e = 0; e < 4; ++e)
        acc[rg][e] += __shfl_xor(acc[rg][e], m, 64);
    #pragma unroll
    for (int e = 0; e < 4; ++e) pacc[e] += __shfl_xor(pacc[e], m, 64);
  }

  if (c == 0) {
    #pragma unroll
    for (int rg = 0; rg < 4; ++rg)
      #pragma unroll
      for (int e = 0; e < 4; ++e)
        lsum[w][rg * 16 + (q << 2) + e] = acc[rg][e];
    #pragma unroll
    for (int e = 0; e < 4; ++e) lpos[w][(q << 2) + e] = pacc[e];
  }
  __syncthreads();

  if (threadIdx.x < 64) {
    const int t = threadIdx.x;
    float s = lsum[0][t] + lsum[1][t] + lsum[2][t] + lsum[3][t];
    atomicAdd(&rowsum[R0 + t], s);
    if (ipb != -99)                     // this cell owns the positive cols
      rowpos[R0 + t] = lpos[t >> 4][t & 15];
  }
  __syncthreads();                      // protect lsum/lpos reuse (2nd cell)
}

// ---------------- phase 3: tot = rowsum - 1; lse = 5 + log(tot); mean -------
__device__ __forceinline__ void do_finish(
    int blk, const float* __restrict__ rowsum, const float* __restrict__ rowpos,
    float* __restrict__ out)
{
  const int r = blk * 256 + threadIdx.x;
  float tot = rowsum[r] - 1.0f;
  float v = 5.0f + logf(tot) - rowpos[r & 4095];
  #pragma unroll
  for (int m = 1; m < 64; m <<= 1) v += __shfl_xor(v, m, 64);
  __shared__ float red[4];
  if ((threadIdx.x & 63) == 0) red[threadIdx.x >> 6] = v;
  __syncthreads();
  if (threadIdx.x == 0)
    atomicAdd(out, (red[0] + red[1] + red[2] + red[3]) * (1.0f / 8192.0f));
}

// ---------------- fused cooperative kernel: 1024 blocks, 4/CU co-resident ---
__global__ __launch_bounds__(256, 4) void k_fused(
    const float* __restrict__ emb_i, const float* __restrict__ emb_j,
    unsigned char* __restrict__ z, float* __restrict__ rowsum,
    float* __restrict__ rowpos, float* __restrict__ out)
{
  if (blockIdx.x < 512)
    do_normalize(blockIdx.x, emb_i, emb_j, z, rowsum, out);
  __threadfence();
  cg::this_grid().sync();

  // 1088 cells over 1024 blocks: blocks 0..63 take a second cell
  #pragma unroll 1
  for (int cell = blockIdx.x; cell < 1088; cell += 1024)
    do_cell(cell, z, rowsum, rowpos);

  __threadfence();
  cg::this_grid().sync();
  if (blockIdx.x < 32)
    do_finish(blockIdx.x, rowsum, rowpos, out);
}

// ---------------- fallback path: identical 3-kernel structure ---------------
__global__ __launch_bounds__(256) void k_normalize(
    const float* __restrict__ emb_i, const float* __restrict__ emb_j,
    unsigned char* __restrict__ z, float* __restrict__ rowsum,
    float* __restrict__ out)
{
  do_normalize(blockIdx.x, emb_i, emb_j, z, rowsum, out);
}

__global__ __launch_bounds__(256, 4) void k_simlse(
    const unsigned char* __restrict__ z,
    float* __restrict__ rowsum, float* __restrict__ rowpos)
{
  do_cell(blockIdx.x, z, rowsum, rowpos);
}

__global__ __launch_bounds__(256) void k_finish(
    const float* __restrict__ rowsum, const float* __restrict__ rowpos,
    float* __restrict__ out)
{
  do_finish(blockIdx.x, rowsum, rowpos, out);
}

extern "C" void kernel_launch(void* const* d_in, const int* in_sizes, int n_in,
                              void* d_out, int out_size, void* d_ws, size_t ws_size,
                              hipStream_t stream) {
  const float* emb_i = (const float*)d_in[0];
  const float* emb_j = (const float*)d_in[1];
  unsigned char* z = (unsigned char*)d_ws;                         // 8192*128*1 = 1 MB (fp8, swizzled)
  float* rowsum = (float*)((char*)d_ws + (1 << 20));               // [8192] = 32 KB
  float* rowpos = rowsum + 8192;                                   // [4096] = 16 KB
  float* out = (float*)d_out;

  void* args[] = {(void*)&emb_i, (void*)&emb_j, (void*)&z,
                  (void*)&rowsum, (void*)&rowpos, (void*)&out};
  hipError_t err = hipLaunchCooperativeKernel(
      reinterpret_cast<const void*>(&k_fused), dim3(1024), dim3(256),
      args, 0, stream);
  if (err != hipSuccess) {
    (void)hipGetLastError();            // clear sticky error, take old path
    k_normalize<<<512, 256, 0, stream>>>(emb_i, emb_j, z, rowsum, out);
    k_simlse<<<1088, 256, 0, stream>>>(z, rowsum, rowpos);
    k_finish<<<32, 256, 0, stream>>>(rowsum, rowpos, out);
  }
}

// Round 2
// 419.241 us; speedup vs baseline: 1.1983x; 1.1983x over previous
//
#include <hip/hip_runtime.h>
#include <hip/hip_bf16.h>
#include <hip/hip_fp8.h>
#include <hip/hip_cooperative_groups.h>

namespace cg = cooperative_groups;

typedef __attribute__((ext_vector_type(4))) float f32x4;
typedef long long i64;

// exp(v/T - 5) with T=0.2  ==  exp2( (v-1) * 5*log2(e) )
#define EXP_SCALE 7.213475204444817f

__device__ __forceinline__ float fast_exp2(float x) {
#if __has_builtin(__builtin_amdgcn_exp2f)
  return __builtin_amdgcn_exp2f(x);
#else
  return exp2f(x);
#endif
}

// z is stored as fp8 e4m3, SWIZZLED in MFMA-fragment order (byte units):
//   byte addr = tile*2048 + kk*512 + slot*8 + rem
// tile = row>>4, c = row&15; element e: kk = e>>5, q = (e>>3)&3, rem = e&7,
// slot = q*16 + c. A wave (lane = q*16+c) loads one (tile,kk) fragment as
// one contiguous 512B load (8B/lane dwordx2).

// ---------------- phase 1: L2-normalize one 16-row tile -> swizzled fp8 z ----
__device__ __forceinline__ void do_normalize(
    int tile, const float* __restrict__ emb_i, const float* __restrict__ emb_j,
    unsigned char* __restrict__ z, float* __restrict__ rowsum,
    float* __restrict__ out)
{
  if (tile == 0 && threadIdx.x == 0) out[0] = 0.0f;
  if (threadIdx.x < 16) rowsum[(tile << 4) + threadIdx.x] = 0.0f;
  const int t = threadIdx.x;
  const int c = t >> 4;               // row within tile (0..15)
  const int sub = t & 15;             // 8-element block within row
  const int row = (tile << 4) + c;
  const float* src = (row < 4096) ? (emb_i + row * 128) : (emb_j + (row - 4096) * 128);
  float4 v0 = reinterpret_cast<const float4*>(src)[sub * 2];
  float4 v1 = reinterpret_cast<const float4*>(src)[sub * 2 + 1];
  float ss = v0.x*v0.x + v0.y*v0.y + v0.z*v0.z + v0.w*v0.w
           + v1.x*v1.x + v1.y*v1.y + v1.z*v1.z + v1.w*v1.w;
  #pragma unroll
  for (int m = 1; m < 16; m <<= 1) ss += __shfl_xor(ss, m, 64);
  float rinv = 1.0f / sqrtf(ss);
  unsigned char st[8];
  st[0] = __hip_fp8_e4m3(v0.x * rinv).__x;
  st[1] = __hip_fp8_e4m3(v0.y * rinv).__x;
  st[2] = __hip_fp8_e4m3(v0.z * rinv).__x;
  st[3] = __hip_fp8_e4m3(v0.w * rinv).__x;
  st[4] = __hip_fp8_e4m3(v1.x * rinv).__x;
  st[5] = __hip_fp8_e4m3(v1.y * rinv).__x;
  st[6] = __hip_fp8_e4m3(v1.z * rinv).__x;
  st[7] = __hip_fp8_e4m3(v1.w * rinv).__x;
  // swizzled dst: kk = sub>>2, q = sub&3, slot = q*16 + c
  unsigned char* dst = z + tile * 2048 + (sub >> 2) * 512 +
                       (((sub & 3) << 4) + c) * 8;
  *reinterpret_cast<i64*>(dst) = *reinterpret_cast<i64*>(st);
}

// ---------------- phase 2: one 64x512 cell of the sim/exp accumulation ------
// cell exists iff rb < 8(ch+1), ch 0..15 -> 1088 cells (53% of full work).
// A fragments straight from global (16 x 512B contiguous wave loads). Row-sums
// atomicAdd into rowsum; strictly-upper cells also atomicAdd column sums
// (transposed rows). Diagonal exp term (==1 for unit rows) kept; finish
// subtracts 1.
// MUST be force-inlined: as an out-of-line callee this spills ~50 VGPRs to
// scratch (round-1 regression: 64-VGPR ABI budget, 95 MB scratch traffic).
__device__ __forceinline__ void do_cell(
    int bid, const unsigned char* __restrict__ z,
    float* __restrict__ rowsum, float* __restrict__ rowpos)
{
  const int w = threadIdx.x >> 6;
  const int lane = threadIdx.x & 63;
  const int q = lane >> 4;
  const int c = lane & 15;

  // cell id -> (ch, rb): start(ch) = 4ch(ch+1), cells(ch) = 8(ch+1)
  int ch = 0;
  while (bid >= 4 * (ch + 1) * (ch + 2)) ++ch;
  const int rb = bid - 4 * ch * (ch + 1);          // 0 .. 8ch+7
  const int R0 = rb << 6;                          // 64-row block
  const bool upper = (rb < (ch << 3));             // strictly above diagonal band

  // ---- A fragments straight from global: 16 contiguous 512B loads ----
  i64 a[4][4];
  {
    const unsigned char* ap = z + (R0 >> 4) * 2048 + (lane << 3);
    #pragma unroll
    for (int rg = 0; rg < 4; ++rg)
      #pragma unroll
      for (int kk = 0; kk < 4; ++kk)
        a[rg][kk] = *reinterpret_cast<const i64*>(ap + rg * 2048 + kk * 512);
  }

  float acc[4][4];
  #pragma unroll
  for (int rg = 0; rg < 4; ++rg)
    #pragma unroll
    for (int e = 0; e < 4; ++e) acc[rg][e] = 0.0f;
  float pacc[4] = {0.f, 0.f, 0.f, 0.f};
  float colp[8];
  #pragma unroll
  for (int i = 0; i < 8; ++i) colp[i] = 0.0f;

  __shared__ float lsum[4][64];
  __shared__ float lpos[4][16];

  // wave w walks 16-col tiles ct = 32ch + w + 4i, i = 0..7
  const int ct0 = (ch << 5) + w;
  const unsigned char* bwave = z + ct0 * 2048 + (lane << 3);

  // positive tile: owned by this cell iff its 32-tile chunk matches.
  const int pos0t = ((R0 + 4096) & 8191) >> 4;
  const int ipb = ((pos0t >> 5) == ch) ? ((pos0t & 31) >> 2) : -99;

  i64 b0[4], b1[4];
  auto ldb = [&](i64 (&dst)[4], int idx) {
    const unsigned char* p = bwave + idx * 8192;   // stride 4 tiles = 8KB
    dst[0] = *reinterpret_cast<const i64*>(p);
    dst[1] = *reinterpret_cast<const i64*>(p + 512);
    dst[2] = *reinterpret_cast<const i64*>(p + 1024);
    dst[3] = *reinterpret_cast<const i64*>(p + 1536);
  };

  auto process = [&](const i64 (&bb)[4], int i) {
    f32x4 cc[4];
    #pragma unroll
    for (int rr = 0; rr < 4; ++rr) cc[rr] = f32x4{0.f, 0.f, 0.f, 0.f};
    #pragma unroll
    for (int kk = 0; kk < 4; ++kk)
      #pragma unroll
      for (int rr = 0; rr < 4; ++rr)
        cc[rr] = __builtin_amdgcn_mfma_f32_16x16x32_fp8_fp8(
            a[rr][kk], bb[kk], cc[rr], 0, 0, 0);
    float cp0 = 0.0f, cp1 = 0.0f;       // two chains to cut dep latency
    #pragma unroll
    for (int rr = 0; rr < 4; ++rr)
      #pragma unroll
      for (int e = 0; e < 4; ++e) {
        float tv = fast_exp2(__builtin_fmaf(cc[rr][e], EXP_SCALE, -EXP_SCALE));
        acc[rr][e] += tv;
        if (upper) { if (rr & 1) cp1 += tv; else cp0 += tv; }
      }
    if (upper) colp[i] = cp0 + cp1;     // shfl deferred out of the loop
    if (i == ipb) {                     // rare, wave-uniform
      #pragma unroll
      for (int rr = 0; rr < 4; ++rr) {
        if (rr == w) {
          #pragma unroll
          for (int e = 0; e < 4; ++e)
            if (c == ((q << 2) + e)) pacc[e] = cc[rr][e] * 5.0f;
        }
      }
    }
  };

  ldb(b0, 0);
  #pragma unroll 1
  for (int i = 0; i < 8; i += 2) {
    ldb(b1, i + 1);
    process(b0, i);
    if (i + 2 < 8) ldb(b0, i + 2);
    process(b1, i + 1);
  }

  // Deferred colsum reduction: 8 independent values, shfls pipeline
  if (upper) {
    #pragma unroll
    for (int i = 0; i < 8; ++i) {
      float v = colp[i];
      v += __shfl_xor(v, 16, 64);
      v += __shfl_xor(v, 32, 64);
      if (lane < 16)                    // col = (ct0+4i)*16 + c
        atomicAdd(&rowsum[((ct0 + (i << 2)) << 4) + c], v);
    }
  }

  // Reduce row-sums over the 16 cols per tile (c-group: xor 1,2,4,8)
  #pragma unroll
  for (int m = 1; m < 16; m <<= 1) {
    #pragma unroll
    for (int rg = 0; rg < 4; ++rg)
      #pragma unroll
      for (int e = 0; e < 4; ++e)
        acc[rg][e] += __shfl_xor(acc[rg][e], m, 64);
    #pragma unroll
    for (int e = 0; e < 4; ++e) pacc[e] += __shfl_xor(pacc[e], m, 64);
  }

  if (c == 0) {
    #pragma unroll
    for (int rg = 0; rg < 4; ++rg)
      #pragma unroll
      for (int e = 0; e < 4; ++e)
        lsum[w][rg * 16 + (q << 2) + e] = acc[rg][e];
    #pragma unroll
    for (int e = 0; e < 4; ++e) lpos[w][(q << 2) + e] = pacc[e];
  }
  __syncthreads();

  if (threadIdx.x < 64) {
    const int t = threadIdx.x;
    float s = lsum[0][t] + lsum[1][t] + lsum[2][t] + lsum[3][t];
    atomicAdd(&rowsum[R0 + t], s);
    if (ipb != -99)                     // this cell owns the positive cols
      rowpos[R0 + t] = lpos[t >> 4][t & 15];
  }
  __syncthreads();                      // protect lsum/lpos reuse (2nd cell)
}

// ---------------- phase 3: tot = rowsum - 1; lse = 5 + log(tot); mean -------
__device__ __forceinline__ void do_finish(
    int blk, const float* __restrict__ rowsum, const float* __restrict__ rowpos,
    float* __restrict__ out)
{
  const int r = blk * 256 + threadIdx.x;
  float tot = rowsum[r] - 1.0f;
  float v = 5.0f + logf(tot) - rowpos[r & 4095];
  #pragma unroll
  for (int m = 1; m < 64; m <<= 1) v += __shfl_xor(v, m, 64);
  __shared__ float red[4];
  if ((threadIdx.x & 63) == 0) red[threadIdx.x >> 6] = v;
  __syncthreads();
  if (threadIdx.x == 0)
    atomicAdd(out, (red[0] + red[1] + red[2] + red[3]) * (1.0f / 8192.0f));
}

// ---------------- fused cooperative kernel: 1024 blocks, 4/CU co-resident ---
__global__ __launch_bounds__(256, 4) void k_fused(
    const float* __restrict__ emb_i, const float* __restrict__ emb_j,
    unsigned char* __restrict__ z, float* __restrict__ rowsum,
    float* __restrict__ rowpos, float* __restrict__ out)
{
  if (blockIdx.x < 512)
    do_normalize(blockIdx.x, emb_i, emb_j, z, rowsum, out);
  __threadfence();
  cg::this_grid().sync();

  // 1088 cells over 1024 blocks: blocks 0..63 take a second cell
  #pragma unroll 1
  for (int cell = blockIdx.x; cell < 1088; cell += 1024)
    do_cell(cell, z, rowsum, rowpos);

  __threadfence();
  cg::this_grid().sync();
  if (blockIdx.x < 32)
    do_finish(blockIdx.x, rowsum, rowpos, out);
}

// ---------------- fallback path: identical 3-kernel structure ---------------
__global__ __launch_bounds__(256) void k_normalize(
    const float* __restrict__ emb_i, const float* __restrict__ emb_j,
    unsigned char* __restrict__ z, float* __restrict__ rowsum,
    float* __restrict__ out)
{
  do_normalize(blockIdx.x, emb_i, emb_j, z, rowsum, out);
}

__global__ __launch_bounds__(256, 4) void k_simlse(
    const unsigned char* __restrict__ z,
    float* __restrict__ rowsum, float* __restrict__ rowpos)
{
  do_cell(blockIdx.x, z, rowsum, rowpos);
}

__global__ __launch_bounds__(256) void k_finish(
    const float* __restrict__ rowsum, const float* __restrict__ rowpos,
    float* __restrict__ out)
{
  do_finish(blockIdx.x, rowsum, rowpos, out);
}

extern "C" void kernel_launch(void* const* d_in, const int* in_sizes, int n_in,
                              void* d_out, int out_size, void* d_ws, size_t ws_size,
                              hipStream_t stream) {
  const float* emb_i = (const float*)d_in[0];
  const float* emb_j = (const float*)d_in[1];
  unsigned char* z = (unsigned char*)d_ws;                         // 8192*128*1 = 1 MB (fp8, swizzled)
  float* rowsum = (float*)((char*)d_ws + (1 << 20));               // [8192] = 32 KB
  float* rowpos = rowsum + 8192;                                   // [4096] = 16 KB
  float* out = (float*)d_out;

  void* args[] = {(void*)&emb_i, (void*)&emb_j, (void*)&z,
                  (void*)&rowsum, (void*)&rowpos, (void*)&out};
  hipError_t err = hipLaunchCooperativeKernel(
      reinterpret_cast<const void*>(&k_fused), dim3(1024), dim3(256),
      args, 0, stream);
  if (err != hipSuccess) {
    (void)hipGetLastError();            // clear sticky error, take old path
    k_normalize<<<512, 256, 0, stream>>>(emb_i, emb_j, z, rowsum, out);
    k_simlse<<<1088, 256, 0, stream>>>(z, rowsum, rowpos);
    k_finish<<<32, 256, 0, stream>>>(rowsum, rowpos, out);
  }
}

// Round 3
// 116.283 us; speedup vs baseline: 4.3203x; 3.6054x over previous
//
#include <hip/hip_runtime.h>
#include <hip/hip_bf16.h>
#include <hip/hip_fp8.h>

typedef __attribute__((ext_vector_type(4))) float f32x4;
typedef long long i64;

// exp(v/T - 5) with T=0.2  ==  exp2( (v-1) * 5*log2(e) )
#define EXP_SCALE 7.213475204444817f

__device__ __forceinline__ float fast_exp2(float x) {
#if __has_builtin(__builtin_amdgcn_exp2f)
  return __builtin_amdgcn_exp2f(x);
#else
  return exp2f(x);
#endif
}

// z is stored as fp8 e4m3, SWIZZLED in MFMA-fragment order (byte units):
//   byte addr = tile*2048 + kk*512 + slot*8 + rem
// tile = row>>4, c = row&15; element e: kk = e>>5, q = (e>>3)&3, rem = e&7,
// slot = q*16 + c. A wave (lane = q*16+c) loads one (tile,kk) fragment as
// one contiguous 512B load (8B/lane dwordx2).

// ---- normalize one 16-row tile -> swizzled fp8 z (agent-coherent stores) ----
// Stores bypass local L2 (sc1) so consumers on other XCDs read fresh data
// from the coherent point after the ready-flag handshake.
__device__ __forceinline__ void norm_tile(
    int tile, const float* __restrict__ emb_i, const float* __restrict__ emb_j,
    unsigned char* __restrict__ z)
{
  const int t = threadIdx.x;
  const int c = t >> 4;               // row within tile (0..15)
  const int sub = t & 15;             // 8-element block within row
  const int row = (tile << 4) + c;
  const float* src = (row < 4096) ? (emb_i + row * 128) : (emb_j + (row - 4096) * 128);
  float4 v0 = reinterpret_cast<const float4*>(src)[sub * 2];
  float4 v1 = reinterpret_cast<const float4*>(src)[sub * 2 + 1];
  float ss = v0.x*v0.x + v0.y*v0.y + v0.z*v0.z + v0.w*v0.w
           + v1.x*v1.x + v1.y*v1.y + v1.z*v1.z + v1.w*v1.w;
  #pragma unroll
  for (int m = 1; m < 16; m <<= 1) ss += __shfl_xor(ss, m, 64);
  float rinv = 1.0f / sqrtf(ss);
  unsigned char st[8];
  st[0] = __hip_fp8_e4m3(v0.x * rinv).__x;
  st[1] = __hip_fp8_e4m3(v0.y * rinv).__x;
  st[2] = __hip_fp8_e4m3(v0.z * rinv).__x;
  st[3] = __hip_fp8_e4m3(v0.w * rinv).__x;
  st[4] = __hip_fp8_e4m3(v1.x * rinv).__x;
  st[5] = __hip_fp8_e4m3(v1.y * rinv).__x;
  st[6] = __hip_fp8_e4m3(v1.z * rinv).__x;
  st[7] = __hip_fp8_e4m3(v1.w * rinv).__x;
  // swizzled dst: kk = sub>>2, q = sub&3, slot = q*16 + c
  unsigned char* dst = z + tile * 2048 + (sub >> 2) * 512 +
                       (((sub & 3) << 4) + c) * 8;
  i64 val;
  __builtin_memcpy(&val, st, 8);
  __hip_atomic_store(reinterpret_cast<i64*>(dst), val,
                     __ATOMIC_RELAXED, __HIP_MEMORY_SCOPE_AGENT);
}

// ---- one 64x512 cell of the sim/exp accumulation (math unchanged) ----------
__device__ __forceinline__ void do_cell_body(
    int ch, int rb, int R0, const unsigned char* __restrict__ z,
    float* __restrict__ rowsum, float* __restrict__ rowpos)
{
  const int w = threadIdx.x >> 6;
  const int lane = threadIdx.x & 63;
  const int q = lane >> 4;
  const int c = lane & 15;
  const bool upper = (rb < (ch << 3));             // strictly above diagonal band

  // ---- A fragments straight from global: 16 contiguous 512B loads ----
  i64 a[4][4];
  {
    const unsigned char* ap = z + (R0 >> 4) * 2048 + (lane << 3);
    #pragma unroll
    for (int rg = 0; rg < 4; ++rg)
      #pragma unroll
      for (int kk = 0; kk < 4; ++kk)
        a[rg][kk] = *reinterpret_cast<const i64*>(ap + rg * 2048 + kk * 512);
  }

  float acc[4][4];
  #pragma unroll
  for (int rg = 0; rg < 4; ++rg)
    #pragma unroll
    for (int e = 0; e < 4; ++e) acc[rg][e] = 0.0f;
  float pacc[4] = {0.f, 0.f, 0.f, 0.f};
  float colp[8];
  #pragma unroll
  for (int i = 0; i < 8; ++i) colp[i] = 0.0f;

  __shared__ float lsum[4][64];
  __shared__ float lpos[4][16];

  // wave w walks 16-col tiles ct = 32ch + w + 4i, i = 0..7
  const int ct0 = (ch << 5) + w;
  const unsigned char* bwave = z + ct0 * 2048 + (lane << 3);

  // positive tile: owned by this cell iff its 32-tile chunk matches.
  const int pos0t = ((R0 + 4096) & 8191) >> 4;
  const int ipb = ((pos0t >> 5) == ch) ? ((pos0t & 31) >> 2) : -99;

  i64 b0[4], b1[4];
  auto ldb = [&](i64 (&dst)[4], int idx) {
    const unsigned char* p = bwave + idx * 8192;   // stride 4 tiles = 8KB
    dst[0] = *reinterpret_cast<const i64*>(p);
    dst[1] = *reinterpret_cast<const i64*>(p + 512);
    dst[2] = *reinterpret_cast<const i64*>(p + 1024);
    dst[3] = *reinterpret_cast<const i64*>(p + 1536);
  };

  auto process = [&](const i64 (&bb)[4], int i) {
    f32x4 cc[4];
    #pragma unroll
    for (int rr = 0; rr < 4; ++rr) cc[rr] = f32x4{0.f, 0.f, 0.f, 0.f};
    #pragma unroll
    for (int kk = 0; kk < 4; ++kk)
      #pragma unroll
      for (int rr = 0; rr < 4; ++rr)
        cc[rr] = __builtin_amdgcn_mfma_f32_16x16x32_fp8_fp8(
            a[rr][kk], bb[kk], cc[rr], 0, 0, 0);
    float cp0 = 0.0f, cp1 = 0.0f;       // two chains to cut dep latency
    #pragma unroll
    for (int rr = 0; rr < 4; ++rr)
      #pragma unroll
      for (int e = 0; e < 4; ++e) {
        float tv = fast_exp2(__builtin_fmaf(cc[rr][e], EXP_SCALE, -EXP_SCALE));
        acc[rr][e] += tv;
        if (upper) { if (rr & 1) cp1 += tv; else cp0 += tv; }
      }
    if (upper) colp[i] = cp0 + cp1;     // shfl deferred out of the loop
    if (i == ipb) {                     // rare, wave-uniform
      #pragma unroll
      for (int rr = 0; rr < 4; ++rr) {
        if (rr == w) {
          #pragma unroll
          for (int e = 0; e < 4; ++e)
            if (c == ((q << 2) + e)) pacc[e] = cc[rr][e] * 5.0f;
        }
      }
    }
  };

  ldb(b0, 0);
  #pragma unroll 1
  for (int i = 0; i < 8; i += 2) {
    ldb(b1, i + 1);
    process(b0, i);
    if (i + 2 < 8) ldb(b0, i + 2);
    process(b1, i + 1);
  }

  // Deferred colsum reduction: 8 independent values, shfls pipeline
  if (upper) {
    #pragma unroll
    for (int i = 0; i < 8; ++i) {
      float v = colp[i];
      v += __shfl_xor(v, 16, 64);
      v += __shfl_xor(v, 32, 64);
      if (lane < 16)                    // col = (ct0+4i)*16 + c
        atomicAdd(&rowsum[((ct0 + (i << 2)) << 4) + c], v);
    }
  }

  // Reduce row-sums over the 16 cols per tile (c-group: xor 1,2,4,8)
  #pragma unroll
  for (int m = 1; m < 16; m <<= 1) {
    #pragma unroll
    for (int rg = 0; rg < 4; ++rg)
      #pragma unroll
      for (int e = 0; e < 4; ++e)
        acc[rg][e] += __shfl_xor(acc[rg][e], m, 64);
    #pragma unroll
    for (int e = 0; e < 4; ++e) pacc[e] += __shfl_xor(pacc[e], m, 64);
  }

  if (c == 0) {
    #pragma unroll
    for (int rg = 0; rg < 4; ++rg)
      #pragma unroll
      for (int e = 0; e < 4; ++e)
        lsum[w][rg * 16 + (q << 2) + e] = acc[rg][e];
    #pragma unroll
    for (int e = 0; e < 4; ++e) lpos[w][(q << 2) + e] = pacc[e];
  }
  __syncthreads();

  if (threadIdx.x < 64) {
    const int t = threadIdx.x;
    float s = lsum[0][t] + lsum[1][t] + lsum[2][t] + lsum[3][t];
    atomicAdd(&rowsum[R0 + t], s);
    if (ipb != -99)                     // this cell owns the positive cols
      __hip_atomic_store(&rowpos[R0 + t], lpos[t >> 4][t & 15],
                         __ATOMIC_RELAXED, __HIP_MEMORY_SCOPE_AGENT);
  }
}

// ---- single fused kernel: 1088 blocks, plain launch, flag handshake --------
// ctrs[0] = ready (tiles produced), ctrs[32] = done ticket (128B apart).
// rowsum + ctrs are zeroed by hipMemsetAsync before this kernel.
__global__ __launch_bounds__(256, 4) void k_all(
    const float* __restrict__ emb_i, const float* __restrict__ emb_j,
    unsigned char* __restrict__ z, float* __restrict__ rowsum,
    int* __restrict__ ctrs, float* __restrict__ rowpos,
    float* __restrict__ out)
{
  const int bid = blockIdx.x;

  // ---- phase A: blocks 0..511 each produce one 16-row tile of z ----
  if (bid < 512) {
    norm_tile(bid, emb_i, emb_j, z);
    asm volatile("s_waitcnt vmcnt(0)" ::: "memory");   // stores acked at coherent point
    if (threadIdx.x == 0)
      __hip_atomic_fetch_add(&ctrs[0], 1, __ATOMIC_RELAXED,
                             __HIP_MEMORY_SCOPE_AGENT);
  }

  // cell id -> (ch, rb): start(ch) = 4ch(ch+1), cells(ch) = 8(ch+1)
  int ch = 0;
  while (bid >= 4 * (ch + 1) * (ch + 2)) ++ch;
  const int rb = bid - 4 * ch * (ch + 1);          // 0 .. 8ch+7
  const int R0 = rb << 6;                          // 64-row block

  // ---- wait for all 512 tiles (bounded spin; producers produced first) ----
  __shared__ int sflag;
  if (threadIdx.x == 0) {
    int it = 0, fb = 0;
    while (__hip_atomic_load(&ctrs[0], __ATOMIC_RELAXED,
                             __HIP_MEMORY_SCOPE_AGENT) < 512) {
      __builtin_amdgcn_s_sleep(8);
      if (++it > (1 << 17)) { fb = 1; break; }
    }
    sflag = fb;
  }
  __syncthreads();
  if (sflag) {
    // Timeout (pathological dispatch order): self-produce the 36 tiles this
    // cell reads. Idempotent — identical bytes, benign if racing producers.
    #pragma unroll 1
    for (int k = 0; k < 4; ++k) norm_tile((R0 >> 4) + k, emb_i, emb_j, z);
    #pragma unroll 1
    for (int k = 0; k < 32; ++k) norm_tile((ch << 5) + k, emb_i, emb_j, z);
    asm volatile("s_waitcnt vmcnt(0)" ::: "memory");
    __syncthreads();
  }

  // ---- phase B: the cell (unchanged math) ----
  do_cell_body(ch, rb, R0, z, rowsum, rowpos);

  // barrier drains each wave's outstanding atomics (vmcnt) before ticket
  __syncthreads();
  __shared__ int sfin;
  if (threadIdx.x == 0) {
    int old = __hip_atomic_fetch_add(&ctrs[32], 1, __ATOMIC_RELAXED,
                                     __HIP_MEMORY_SCOPE_AGENT);
    sfin = (old == 1087);
  }
  __syncthreads();

  // ---- phase C: last block computes the loss (coherent reads) ----
  if (sfin) {
    float part = 0.0f;
    #pragma unroll 1
    for (int r = threadIdx.x; r < 8192; r += 256) {
      float tot = __hip_atomic_load(&rowsum[r], __ATOMIC_RELAXED,
                                    __HIP_MEMORY_SCOPE_AGENT) - 1.0f;
      float p = __hip_atomic_load(&rowpos[r & 4095], __ATOMIC_RELAXED,
                                  __HIP_MEMORY_SCOPE_AGENT);
      part += 5.0f + logf(tot) - p;
    }
    #pragma unroll
    for (int m = 1; m < 64; m <<= 1) part += __shfl_xor(part, m, 64);
    __shared__ float red[4];
    if ((threadIdx.x & 63) == 0) red[threadIdx.x >> 6] = part;
    __syncthreads();
    if (threadIdx.x == 0)
      out[0] = (red[0] + red[1] + red[2] + red[3]) * (1.0f / 8192.0f);
  }
}

extern "C" void kernel_launch(void* const* d_in, const int* in_sizes, int n_in,
                              void* d_out, int out_size, void* d_ws, size_t ws_size,
                              hipStream_t stream) {
  const float* emb_i = (const float*)d_in[0];
  const float* emb_j = (const float*)d_in[1];
  unsigned char* z = (unsigned char*)d_ws;                         // 1 MB fp8, swizzled
  float* rowsum = (float*)((char*)d_ws + (1 << 20));               // [8192] = 32 KB
  int* ctrs = (int*)((char*)d_ws + (1 << 20) + 32768);             // 256 B (ready, done)
  float* rowpos = (float*)((char*)d_ws + (1 << 20) + 33024);       // [4096] = 16 KB
  float* out = (float*)d_out;

  // zero rowsum + counters (stream-ordered, graph-capture legal)
  hipMemsetAsync((char*)d_ws + (1 << 20), 0, 33024, stream);
  k_all<<<1088, 256, 0, stream>>>(emb_i, emb_j, z, rowsum, ctrs, rowpos, out);
}

// Round 4
// 88.328 us; speedup vs baseline: 5.6877x; 1.3165x over previous
//
#include <hip/hip_runtime.h>
#include <hip/hip_bf16.h>
#include <hip/hip_fp8.h>

typedef __attribute__((ext_vector_type(4))) float f32x4;
typedef long long i64;

// exp(v/T - 5) with T=0.2  ==  exp2( (v-1) * 5*log2(e) )
#define EXP_SCALE 7.213475204444817f

__device__ __forceinline__ float fast_exp2(float x) {
#if __has_builtin(__builtin_amdgcn_exp2f)
  return __builtin_amdgcn_exp2f(x);
#else
  return exp2f(x);
#endif
}

// z is stored as fp8 e4m3, SWIZZLED in MFMA-fragment order (byte units):
//   byte addr = tile*2048 + kk*512 + slot*8 + rem
// tile = row>>4, c = row&15; element e: kk = e>>5, q = (e>>3)&3, rem = e&7,
// slot = q*16 + c. A wave (lane = q*16+c) loads one (tile,kk) fragment as
// one contiguous 512B load (8B/lane dwordx2).

// Kernel 1: L2-normalize rows -> swizzled fp8 z (PLAIN coalesced stores; the
// kernel boundary provides cross-XCD visibility -- round 3 showed agent-scope
// per-8B stores + in-kernel spin cost ~50us vs ~6us for a boundary).
// Also zeroes rowsum, the done-ticket, and out[0].
__global__ __launch_bounds__(256) void k_normalize(
    const float* __restrict__ emb_i, const float* __restrict__ emb_j,
    unsigned char* __restrict__ z, float* __restrict__ rowsum,
    int* __restrict__ ctrs, float* __restrict__ out)
{
  if (blockIdx.x == 0 && threadIdx.x == 0) { out[0] = 0.0f; ctrs[0] = 0; }
  if (threadIdx.x < 16) rowsum[(blockIdx.x << 4) + threadIdx.x] = 0.0f;
  const int t = threadIdx.x;
  const int c = t >> 4;               // row within tile (0..15)
  const int sub = t & 15;             // 8-element block within row
  const int row = (blockIdx.x << 4) + c;
  const float* src = (row < 4096) ? (emb_i + row * 128) : (emb_j + (row - 4096) * 128);
  float4 v0 = reinterpret_cast<const float4*>(src)[sub * 2];
  float4 v1 = reinterpret_cast<const float4*>(src)[sub * 2 + 1];
  float ss = v0.x*v0.x + v0.y*v0.y + v0.z*v0.z + v0.w*v0.w
           + v1.x*v1.x + v1.y*v1.y + v1.z*v1.z + v1.w*v1.w;
  #pragma unroll
  for (int m = 1; m < 16; m <<= 1) ss += __shfl_xor(ss, m, 64);
  float rinv = 1.0f / sqrtf(ss);
  unsigned char st[8];
  st[0] = __hip_fp8_e4m3(v0.x * rinv).__x;
  st[1] = __hip_fp8_e4m3(v0.y * rinv).__x;
  st[2] = __hip_fp8_e4m3(v0.z * rinv).__x;
  st[3] = __hip_fp8_e4m3(v0.w * rinv).__x;
  st[4] = __hip_fp8_e4m3(v1.x * rinv).__x;
  st[5] = __hip_fp8_e4m3(v1.y * rinv).__x;
  st[6] = __hip_fp8_e4m3(v1.z * rinv).__x;
  st[7] = __hip_fp8_e4m3(v1.w * rinv).__x;
  // swizzled dst: kk = sub>>2, q = sub&3, slot = q*16 + c
  unsigned char* dst = z + blockIdx.x * 2048 + (sub >> 2) * 512 +
                       (((sub & 3) << 4) + c) * 8;
  *reinterpret_cast<i64*>(dst) = *reinterpret_cast<i64*>(st);
}

// Kernel 2 (symmetric, fp8 MFMA) + folded finish: cell = 64 rows x 512 cols,
// launched iff rb < 8(ch+1), ch 0..15 -> 1088 cells (53% of full work).
// A fragments straight from global (16 x 512B contiguous wave loads). Row-sums
// atomicAdd into rowsum; strictly-upper cells also atomicAdd column sums
// (transposed rows). Diagonal exp term (==1 for unit rows) kept; finish
// subtracts 1. After all atomics drain, a done-ticket elects the last block
// to compute the loss (device-scope reads; pattern validated round 3).
__global__ __launch_bounds__(256, 4) void k_simfin(
    const unsigned char* __restrict__ z,
    float* __restrict__ rowsum,   // [8192], atomic accumulation
    float* __restrict__ rowpos,   // [4096] (row r>=4096 mirrors r-4096)
    int* __restrict__ ctrs, float* __restrict__ out)
{
  const int w = threadIdx.x >> 6;
  const int lane = threadIdx.x & 63;
  const int q = lane >> 4;
  const int c = lane & 15;

  // cell id -> (ch, rb): start(ch) = 4ch(ch+1), cells(ch) = 8(ch+1)
  int ch = 0;
  while ((int)blockIdx.x >= 4 * (ch + 1) * (ch + 2)) ++ch;
  const int rb = blockIdx.x - 4 * ch * (ch + 1);   // 0 .. 8ch+7
  const int R0 = rb << 6;                          // 64-row block
  const bool upper = (rb < (ch << 3));             // strictly above diagonal band

  // ---- A fragments straight from global: 16 contiguous 512B loads ----
  i64 a[4][4];
  {
    const unsigned char* ap = z + (R0 >> 4) * 2048 + (lane << 3);
    #pragma unroll
    for (int rg = 0; rg < 4; ++rg)
      #pragma unroll
      for (int kk = 0; kk < 4; ++kk)
        a[rg][kk] = *reinterpret_cast<const i64*>(ap + rg * 2048 + kk * 512);
  }

  float acc[4][4];
  #pragma unroll
  for (int rg = 0; rg < 4; ++rg)
    #pragma unroll
    for (int e = 0; e < 4; ++e) acc[rg][e] = 0.0f;
  float pacc[4] = {0.f, 0.f, 0.f, 0.f};
  float colp[8];
  #pragma unroll
  for (int i = 0; i < 8; ++i) colp[i] = 0.0f;

  __shared__ float lsum[4][64];
  __shared__ float lpos[4][16];

  // wave w walks 16-col tiles ct = 32ch + w + 4i, i = 0..7
  const int ct0 = (ch << 5) + w;
  const unsigned char* bwave = z + ct0 * 2048 + (lane << 3);

  // positive tile: owned by this cell iff its 32-tile chunk matches.
  const int pos0t = ((R0 + 4096) & 8191) >> 4;
  const int ipb = ((pos0t >> 5) == ch) ? ((pos0t & 31) >> 2) : -99;

  i64 b0[4], b1[4];
  auto ldb = [&](i64 (&dst)[4], int idx) {
    const unsigned char* p = bwave + idx * 8192;   // stride 4 tiles = 8KB
    dst[0] = *reinterpret_cast<const i64*>(p);
    dst[1] = *reinterpret_cast<const i64*>(p + 512);
    dst[2] = *reinterpret_cast<const i64*>(p + 1024);
    dst[3] = *reinterpret_cast<const i64*>(p + 1536);
  };

  auto process = [&](const i64 (&bb)[4], int i) {
    f32x4 cc[4];
    #pragma unroll
    for (int rr = 0; rr < 4; ++rr) cc[rr] = f32x4{0.f, 0.f, 0.f, 0.f};
    #pragma unroll
    for (int kk = 0; kk < 4; ++kk)
      #pragma unroll
      for (int rr = 0; rr < 4; ++rr)
        cc[rr] = __builtin_amdgcn_mfma_f32_16x16x32_fp8_fp8(
            a[rr][kk], bb[kk], cc[rr], 0, 0, 0);
    float cp0 = 0.0f, cp1 = 0.0f;       // two chains to cut dep latency
    #pragma unroll
    for (int rr = 0; rr < 4; ++rr)
      #pragma unroll
      for (int e = 0; e < 4; ++e) {
        float tv = fast_exp2(__builtin_fmaf(cc[rr][e], EXP_SCALE, -EXP_SCALE));
        acc[rr][e] += tv;
        if (upper) { if (rr & 1) cp1 += tv; else cp0 += tv; }
      }
    if (upper) colp[i] = cp0 + cp1;     // shfl deferred out of the loop
    if (i == ipb) {                     // rare, wave-uniform
      #pragma unroll
      for (int rr = 0; rr < 4; ++rr) {
        if (rr == w) {
          #pragma unroll
          for (int e = 0; e < 4; ++e)
            if (c == ((q << 2) + e)) pacc[e] = cc[rr][e] * 5.0f;
        }
      }
    }
  };

  ldb(b0, 0);
  #pragma unroll 1
  for (int i = 0; i < 8; i += 2) {
    ldb(b1, i + 1);
    process(b0, i);
    if (i + 2 < 8) ldb(b0, i + 2);
    process(b1, i + 1);
  }

  // Deferred colsum reduction: 8 independent values, shfls pipeline
  if (upper) {
    #pragma unroll
    for (int i = 0; i < 8; ++i) {
      float v = colp[i];
      v += __shfl_xor(v, 16, 64);
      v += __shfl_xor(v, 32, 64);
      if (lane < 16)                    // col = (ct0+4i)*16 + c
        atomicAdd(&rowsum[((ct0 + (i << 2)) << 4) + c], v);
    }
  }

  // Reduce row-sums over the 16 cols per tile (c-group: xor 1,2,4,8)
  #pragma unroll
  for (int m = 1; m < 16; m <<= 1) {
    #pragma unroll
    for (int rg = 0; rg < 4; ++rg)
      #pragma unroll
      for (int e = 0; e < 4; ++e)
        acc[rg][e] += __shfl_xor(acc[rg][e], m, 64);
    #pragma unroll
    for (int e = 0; e < 4; ++e) pacc[e] += __shfl_xor(pacc[e], m, 64);
  }

  if (c == 0) {
    #pragma unroll
    for (int rg = 0; rg < 4; ++rg)
      #pragma unroll
      for (int e = 0; e < 4; ++e)
        lsum[w][rg * 16 + (q << 2) + e] = acc[rg][e];
    #pragma unroll
    for (int e = 0; e < 4; ++e) lpos[w][(q << 2) + e] = pacc[e];
  }
  __syncthreads();

  if (threadIdx.x < 64) {
    const int t = threadIdx.x;
    float s = lsum[0][t] + lsum[1][t] + lsum[2][t] + lsum[3][t];
    atomicAdd(&rowsum[R0 + t], s);
    if (ipb != -99)                     // this cell owns the positive cols
      __hip_atomic_store(&rowpos[R0 + t], lpos[t >> 4][t & 15],
                         __ATOMIC_RELAXED, __HIP_MEMORY_SCOPE_AGENT);
  }

  // ---- folded finish: compiler emits s_waitcnt vmcnt(0) before s_barrier,
  // so after this barrier every lane's atomics are acked at the coherent
  // point; the ticket then orders blocks.
  __syncthreads();
  __shared__ int sfin;
  if (threadIdx.x == 0) {
    int old = __hip_atomic_fetch_add(&ctrs[0], 1, __ATOMIC_RELAXED,
                                     __HIP_MEMORY_SCOPE_AGENT);
    sfin = (old == 1087);
  }
  __syncthreads();

  if (sfin) {                           // last block computes the loss alone
    float part = 0.0f;
    #pragma unroll 1
    for (int r = threadIdx.x; r < 8192; r += 256) {
      float tot = __hip_atomic_load(&rowsum[r], __ATOMIC_RELAXED,
                                    __HIP_MEMORY_SCOPE_AGENT) - 1.0f;
      float p = __hip_atomic_load(&rowpos[r & 4095], __ATOMIC_RELAXED,
                                  __HIP_MEMORY_SCOPE_AGENT);
      part += 5.0f + logf(tot) - p;
    }
    #pragma unroll
    for (int m = 1; m < 64; m <<= 1) part += __shfl_xor(part, m, 64);
    __shared__ float red[4];
    if ((threadIdx.x & 63) == 0) red[threadIdx.x >> 6] = part;
    __syncthreads();
    if (threadIdx.x == 0)
      out[0] = (red[0] + red[1] + red[2] + red[3]) * (1.0f / 8192.0f);
  }
}

extern "C" void kernel_launch(void* const* d_in, const int* in_sizes, int n_in,
                              void* d_out, int out_size, void* d_ws, size_t ws_size,
                              hipStream_t stream) {
  const float* emb_i = (const float*)d_in[0];
  const float* emb_j = (const float*)d_in[1];
  unsigned char* z = (unsigned char*)d_ws;                         // 8192*128*1 = 1 MB (fp8, swizzled)
  float* rowsum = (float*)((char*)d_ws + (1 << 20));               // [8192] = 32 KB
  float* rowpos = rowsum + 8192;                                   // [4096] = 16 KB
  int* ctrs = (int*)(rowpos + 4096);                               // ticket
  float* out = (float*)d_out;

  k_normalize<<<512, 256, 0, stream>>>(emb_i, emb_j, z, rowsum, ctrs, out);
  k_simfin<<<1088, 256, 0, stream>>>(z, rowsum, rowpos, ctrs, out);
}

// Round 5
// 80.007 us; speedup vs baseline: 6.2792x; 1.1040x over previous
//
#include <hip/hip_runtime.h>
#include <hip/hip_bf16.h>
#include <hip/hip_fp8.h>

typedef __attribute__((ext_vector_type(4))) float f32x4;
typedef long long i64;

// exp(v/T - 5) with T=0.2  ==  exp2( (v-1) * 5*log2(e) )
#define EXP_SCALE 7.213475204444817f

__device__ __forceinline__ float fast_exp2(float x) {
#if __has_builtin(__builtin_amdgcn_exp2f)
  return __builtin_amdgcn_exp2f(x);
#else
  return exp2f(x);
#endif
}

// z is stored as fp8 e4m3, SWIZZLED in MFMA-fragment order (byte units):
//   byte addr = tile*2048 + kk*512 + slot*8 + rem
// tile = row>>4, c = row&15; element e: kk = e>>5, q = (e>>3)&3, rem = e&7,
// slot = q*16 + c. A wave (lane = q*16+c) loads one (tile,kk) fragment as
// one contiguous 512B load (8B/lane dwordx2).

// Kernel 1: L2-normalize rows -> swizzled fp8 z. Zeroes out[0] (k_finish
// accumulates into it; kernel boundary orders the zeroing before k_finish).
// No other init needed: the partial-sum buffers are written before read by
// construction (every (ch,rb)/(ch,rb,col) slot k_finish sums is produced by
// an existing cell exactly once).
__global__ __launch_bounds__(256) void k_normalize(
    const float* __restrict__ emb_i, const float* __restrict__ emb_j,
    unsigned char* __restrict__ z, float* __restrict__ out)
{
  if (blockIdx.x == 0 && threadIdx.x == 0) out[0] = 0.0f;
  const int t = threadIdx.x;
  const int c = t >> 4;               // row within tile (0..15)
  const int sub = t & 15;             // 8-element block within row
  const int row = (blockIdx.x << 4) + c;
  const float* src = (row < 4096) ? (emb_i + row * 128) : (emb_j + (row - 4096) * 128);
  float4 v0 = reinterpret_cast<const float4*>(src)[sub * 2];
  float4 v1 = reinterpret_cast<const float4*>(src)[sub * 2 + 1];
  float ss = v0.x*v0.x + v0.y*v0.y + v0.z*v0.z + v0.w*v0.w
           + v1.x*v1.x + v1.y*v1.y + v1.z*v1.z + v1.w*v1.w;
  #pragma unroll
  for (int m = 1; m < 16; m <<= 1) ss += __shfl_xor(ss, m, 64);
  float rinv = 1.0f / sqrtf(ss);
  unsigned char st[8];
  st[0] = __hip_fp8_e4m3(v0.x * rinv).__x;
  st[1] = __hip_fp8_e4m3(v0.y * rinv).__x;
  st[2] = __hip_fp8_e4m3(v0.z * rinv).__x;
  st[3] = __hip_fp8_e4m3(v0.w * rinv).__x;
  st[4] = __hip_fp8_e4m3(v1.x * rinv).__x;
  st[5] = __hip_fp8_e4m3(v1.y * rinv).__x;
  st[6] = __hip_fp8_e4m3(v1.z * rinv).__x;
  st[7] = __hip_fp8_e4m3(v1.w * rinv).__x;
  // swizzled dst: kk = sub>>2, q = sub&3, slot = q*16 + c
  unsigned char* dst = z + blockIdx.x * 2048 + (sub >> 2) * 512 +
                       (((sub & 3) << 4) + c) * 8;
  *reinterpret_cast<i64*>(dst) = *reinterpret_cast<i64*>(st);
}

// Kernel 2 (symmetric, fp8 MFMA), ATOMIC-FREE: cell = 64 rows x 512 cols,
// cell (ch, rb) exists iff rb < 8(ch+1), ch 0..15 -> 1088 cells (53% of
// full work). Row-sums -> rpart[ch][R0+t] (plain store, unique slot).
// Strictly-upper cells also store transposed col-sums ->
// cpart[2048*ch*(ch-1) + rb*512 + localcol] (unique slot). Diagonal exp
// term (==1 for unit rows) kept; k_finish subtracts 1.
__global__ __launch_bounds__(256, 4) void k_simlse(
    const unsigned char* __restrict__ z,
    float* __restrict__ rpart,    // [16][8192] row partial sums
    float* __restrict__ cpart,    // packed col partials, 491520 floats
    float* __restrict__ rowpos)   // [4096] (row r>=4096 mirrors r-4096)
{
  const int w = threadIdx.x >> 6;
  const int lane = threadIdx.x & 63;
  const int q = lane >> 4;
  const int c = lane & 15;
  const int bid = blockIdx.x;

  // closed-form ch: boundaries bid+1 = (2ch+1)^2 are exact f32 squares;
  // integer fixup guards rounding.
  int ch = (int)((sqrtf((float)(bid + 1)) - 1.0f) * 0.5f);
  if (bid >= 4 * (ch + 1) * (ch + 2)) ++ch;
  else if (bid < 4 * ch * (ch + 1)) --ch;
  const int rb = bid - 4 * ch * (ch + 1);          // 0 .. 8ch+7
  const int R0 = rb << 6;                          // 64-row block
  const bool upper = (rb < (ch << 3));             // strictly above diagonal band

  // ---- A fragments straight from global: 16 contiguous 512B loads ----
  i64 a[4][4];
  {
    const unsigned char* ap = z + (R0 >> 4) * 2048 + (lane << 3);
    #pragma unroll
    for (int rg = 0; rg < 4; ++rg)
      #pragma unroll
      for (int kk = 0; kk < 4; ++kk)
        a[rg][kk] = *reinterpret_cast<const i64*>(ap + rg * 2048 + kk * 512);
  }

  float acc[4][4];
  #pragma unroll
  for (int rg = 0; rg < 4; ++rg)
    #pragma unroll
    for (int e = 0; e < 4; ++e) acc[rg][e] = 0.0f;
  float pacc[4] = {0.f, 0.f, 0.f, 0.f};
  float colp[8];
  #pragma unroll
  for (int i = 0; i < 8; ++i) colp[i] = 0.0f;

  __shared__ float lsum[4][64];
  __shared__ float lpos[4][16];

  // wave w walks 16-col tiles ct = 32ch + w + 4i, i = 0..7
  const int ct0 = (ch << 5) + w;
  const unsigned char* bwave = z + ct0 * 2048 + (lane << 3);

  // positive tile: owned by this cell iff its 32-tile chunk matches.
  const int pos0t = ((R0 + 4096) & 8191) >> 4;
  const int ipb = ((pos0t >> 5) == ch) ? ((pos0t & 31) >> 2) : -99;

  i64 b0[4], b1[4];
  auto ldb = [&](i64 (&dst)[4], int idx) {
    const unsigned char* p = bwave + idx * 8192;   // stride 4 tiles = 8KB
    dst[0] = *reinterpret_cast<const i64*>(p);
    dst[1] = *reinterpret_cast<const i64*>(p + 512);
    dst[2] = *reinterpret_cast<const i64*>(p + 1024);
    dst[3] = *reinterpret_cast<const i64*>(p + 1536);
  };

  auto process = [&](const i64 (&bb)[4], int i) {
    f32x4 cc[4];
    #pragma unroll
    for (int rr = 0; rr < 4; ++rr) cc[rr] = f32x4{0.f, 0.f, 0.f, 0.f};
    #pragma unroll
    for (int kk = 0; kk < 4; ++kk)
      #pragma unroll
      for (int rr = 0; rr < 4; ++rr)
        cc[rr] = __builtin_amdgcn_mfma_f32_16x16x32_fp8_fp8(
            a[rr][kk], bb[kk], cc[rr], 0, 0, 0);
    float cp0 = 0.0f, cp1 = 0.0f;       // two chains to cut dep latency
    #pragma unroll
    for (int rr = 0; rr < 4; ++rr)
      #pragma unroll
      for (int e = 0; e < 4; ++e) {
        float tv = fast_exp2(__builtin_fmaf(cc[rr][e], EXP_SCALE, -EXP_SCALE));
        acc[rr][e] += tv;
        if (upper) { if (rr & 1) cp1 += tv; else cp0 += tv; }
      }
    if (upper) colp[i] = cp0 + cp1;     // shfl deferred out of the loop
    if (i == ipb) {                     // rare, wave-uniform
      #pragma unroll
      for (int rr = 0; rr < 4; ++rr) {
        if (rr == w) {
          #pragma unroll
          for (int e = 0; e < 4; ++e)
            if (c == ((q << 2) + e)) pacc[e] = cc[rr][e] * 5.0f;
        }
      }
    }
  };

  ldb(b0, 0);
  #pragma unroll 1
  for (int i = 0; i < 8; i += 2) {
    ldb(b1, i + 1);
    process(b0, i);
    if (i + 2 < 8) ldb(b0, i + 2);
    process(b1, i + 1);
  }

  // Deferred colsum reduction -> PLAIN stores into this cell's private slice
  if (upper) {
    const int cbase = 2048 * ch * (ch - 1) + (rb << 9);
    #pragma unroll
    for (int i = 0; i < 8; ++i) {
      float v = colp[i];
      v += __shfl_xor(v, 16, 64);
      v += __shfl_xor(v, 32, 64);
      if (lane < 16)                    // local col = (w+4i)*16 + c
        cpart[cbase + ((w + (i << 2)) << 4) + c] = v;
    }
  }

  // Reduce row-sums over the 16 cols per tile (c-group: xor 1,2,4,8)
  #pragma unroll
  for (int m = 1; m < 16; m <<= 1) {
    #pragma unroll
    for (int rg = 0; rg < 4; ++rg)
      #pragma unroll
      for (int e = 0; e < 4; ++e)
        acc[rg][e] += __shfl_xor(acc[rg][e], m, 64);
    #pragma unroll
    for (int e = 0; e < 4; ++e) pacc[e] += __shfl_xor(pacc[e], m, 64);
  }

  if (c == 0) {
    #pragma unroll
    for (int rg = 0; rg < 4; ++rg)
      #pragma unroll
      for (int e = 0; e < 4; ++e)
        lsum[w][rg * 16 + (q << 2) + e] = acc[rg][e];
    #pragma unroll
    for (int e = 0; e < 4; ++e) lpos[w][(q << 2) + e] = pacc[e];
  }
  __syncthreads();

  if (threadIdx.x < 64) {
    const int t = threadIdx.x;
    float s = lsum[0][t] + lsum[1][t] + lsum[2][t] + lsum[3][t];
    rpart[(ch << 13) + R0 + t] = s;     // plain store, unique (ch,row) slot
    if (ipb != -99)                     // this cell owns the positive cols
      rowpos[R0 + t] = lpos[t >> 4][t & 15];
  }
}

// Kernel 3: gather partials. rowsum[r] = sum_{ch=r>>9}^{15} rpart[ch][r]
//   + sum_{rb=0}^{8*(r>>9)-1} cpart[2048*chr*(chr-1) + rb*512 + (r&511)]
// (every summed slot was written by an existing cell; no zero-init needed).
// tot = rowsum - 1 (diag); lse = 5 + log(tot); loss = mean(lse - pos).
__global__ __launch_bounds__(256) void k_finish(
    const float* __restrict__ rpart, const float* __restrict__ cpart,
    const float* __restrict__ rowpos, float* __restrict__ out)
{
  const int r = blockIdx.x * 256 + threadIdx.x;
  const int chr = r >> 9;

  float rs = 0.0f;
  #pragma unroll 4
  for (int ch = chr; ch < 16; ++ch) rs += rpart[(ch << 13) + r];

  const int nrb = chr << 3;                        // always a multiple of 8
  const float* cb = cpart + 2048 * chr * (chr - 1) + (r & 511);
  float cs0 = 0.f, cs1 = 0.f, cs2 = 0.f, cs3 = 0.f;
  #pragma unroll 2
  for (int rb = 0; rb < nrb; rb += 4) {
    cs0 += cb[(rb + 0) << 9];
    cs1 += cb[(rb + 1) << 9];
    cs2 += cb[(rb + 2) << 9];
    cs3 += cb[(rb + 3) << 9];
  }

  float tot = rs + ((cs0 + cs1) + (cs2 + cs3)) - 1.0f;
  float v = 5.0f + logf(tot) - rowpos[r & 4095];
  #pragma unroll
  for (int m = 1; m < 64; m <<= 1) v += __shfl_xor(v, m, 64);
  __shared__ float red[4];
  if ((threadIdx.x & 63) == 0) red[threadIdx.x >> 6] = v;
  __syncthreads();
  if (threadIdx.x == 0)
    atomicAdd(out, (red[0] + red[1] + red[2] + red[3]) * (1.0f / 8192.0f));
}

extern "C" void kernel_launch(void* const* d_in, const int* in_sizes, int n_in,
                              void* d_out, int out_size, void* d_ws, size_t ws_size,
                              hipStream_t stream) {
  const float* emb_i = (const float*)d_in[0];
  const float* emb_j = (const float*)d_in[1];
  unsigned char* z = (unsigned char*)d_ws;                   // 1 MB fp8, swizzled
  float* rpart = (float*)((char*)d_ws + (1 << 20));          // 16*8192*4 = 512 KB
  float* cpart = (float*)((char*)d_ws + (1 << 20) + (512 << 10));   // 1.92 MB
  float* rowpos = (float*)((char*)d_ws + (1 << 20) + (512 << 10) + 1966080);
  float* out = (float*)d_out;

  k_normalize<<<512, 256, 0, stream>>>(emb_i, emb_j, z, out);
  k_simlse<<<1088, 256, 0, stream>>>(z, rpart, cpart, rowpos);
  k_finish<<<32, 256, 0, stream>>>(rpart, cpart, rowpos, out);
}